// Round 9
// baseline (24.994 us; speedup 1.0000x reference)
//
#include <hip/hip_runtime.h>

#define TOT   400000            // B*N total nodes
#define FI    64                // in features
#define HD    16                // hidden dim
#define TILES (TOT / 16)        // 25000 16-node tiles
#define NBLK  2048
#define NWAVE (NBLK * 4)        // 256 threads = 4 waves per block

typedef _Float16 f16x8 __attribute__((ext_vector_type(8)));
typedef float    f32x4 __attribute__((ext_vector_type(4)));

// edge_index.expand(B,2,E).reshape(2,-1) makes row==col elementwise
// (flat idx = b*2E + r*E + e; +8E only shifts b by 4) -> every edge is a
// self-edge -> GCNConv == identity + bias. Network = per-node MLP:
//   out = relu(relu(x@W1+b1)@W2+b2)@Wfc + bfc
//
// Matrix pipe via SWAPPED operands (D = W^T . X^T), m89-verified layouts.
// Round 9: r4 structure + NON-TEMPORAL x loads via clang vector type
// (__builtin_nontemporal_load rejects HIP's struct float4). Tests the
// "read-allocation throttles streaming" theory for 4.7 vs 7.0 TB/s.
__global__ __launch_bounds__(256, 4) void k_mlp_mfma(
        const float* __restrict__ x,
        const float* __restrict__ W1, const float* __restrict__ b1,
        const float* __restrict__ W2, const float* __restrict__ b2,
        const float* __restrict__ Wfc, const float* __restrict__ bfc,
        float* __restrict__ out) {
    const int lane = threadIdx.x & 63;
    const int n    = lane & 15;      // node-in-tile / D col
    const int hi   = lane >> 4;      // 0..3
    const int wid  = blockIdx.x * 4 + (threadIdx.x >> 6);

    // ---- weight fragments (VGPR-resident, wave-uniform source) ----
    f16x8 a1f[2];
#pragma unroll
    for (int ks = 0; ks < 2; ++ks)
#pragma unroll
        for (int i = 0; i < 8; ++i)
            a1f[ks][i] = (_Float16)W1[(ks * 32 + hi * 8 + i) * HD + n];

    f16x8 a2f;
    if (hi < 2) {
#pragma unroll
        for (int i = 0; i < 8; ++i)
            a2f[i] = (_Float16)W2[(hi * 8 + i) * HD + n];
    } else {
#pragma unroll
        for (int i = 0; i < 8; ++i)
            a2f[i] = (_Float16)0.0f;
    }

    const float4 b1p = *reinterpret_cast<const float4*>(b1 + hi * 4);
    const float4 b2p = *reinterpret_cast<const float4*>(b2 + hi * 4);
    const float4 wfp = *reinterpret_cast<const float4*>(Wfc + hi * 4);
    const float  bf  = bfc[0];

    // bpermute source lanes for layer-2 B-fragment assembly
    const int src0 = (((hi * 2)     & 3) * 16 + n) * 4;   // i = 0..3
    const int src1 = (((hi * 2 + 1) & 3) * 16 + n) * 4;   // i = 4..7
    const bool live = (hi < 2);                           // k<16 rows only

    for (int t = wid; t < TILES; t += NWAVE) {
        const float* xrow = x + ((size_t)t * 16 + n) * FI;

        // non-temporal streaming loads (clang vector type, nt flag)
        f32x4 xa = __builtin_nontemporal_load(reinterpret_cast<const f32x4*>(xrow + hi * 8));
        f32x4 xb = __builtin_nontemporal_load(reinterpret_cast<const f32x4*>(xrow + hi * 8 + 4));
        f32x4 xc = __builtin_nontemporal_load(reinterpret_cast<const f32x4*>(xrow + 32 + hi * 8));
        f32x4 xd = __builtin_nontemporal_load(reinterpret_cast<const f32x4*>(xrow + 32 + hi * 8 + 4));

        f16x8 bA, bB;
        bA[0] = (_Float16)xa[0]; bA[1] = (_Float16)xa[1];
        bA[2] = (_Float16)xa[2]; bA[3] = (_Float16)xa[3];
        bA[4] = (_Float16)xb[0]; bA[5] = (_Float16)xb[1];
        bA[6] = (_Float16)xb[2]; bA[7] = (_Float16)xb[3];
        bB[0] = (_Float16)xc[0]; bB[1] = (_Float16)xc[1];
        bB[2] = (_Float16)xc[2]; bB[3] = (_Float16)xc[3];
        bB[4] = (_Float16)xd[0]; bB[5] = (_Float16)xd[1];
        bB[6] = (_Float16)xd[2]; bB[7] = (_Float16)xd[3];

        f32x4 acc = {0.f, 0.f, 0.f, 0.f};
        acc = __builtin_amdgcn_mfma_f32_16x16x32_f16(a1f[0], bA, acc, 0, 0, 0);
        acc = __builtin_amdgcn_mfma_f32_16x16x32_f16(a1f[1], bB, acc, 0, 0, 0);

        float t0 = fmaxf(acc[0] + b1p.x, 0.f);
        float t1 = fmaxf(acc[1] + b1p.y, 0.f);
        float t2 = fmaxf(acc[2] + b1p.z, 0.f);
        float t3 = fmaxf(acc[3] + b1p.w, 0.f);

        float g0 = __int_as_float(__builtin_amdgcn_ds_bpermute(src0, __float_as_int(t0)));
        float g1 = __int_as_float(__builtin_amdgcn_ds_bpermute(src0, __float_as_int(t1)));
        float g2 = __int_as_float(__builtin_amdgcn_ds_bpermute(src0, __float_as_int(t2)));
        float g3 = __int_as_float(__builtin_amdgcn_ds_bpermute(src0, __float_as_int(t3)));
        float g4 = __int_as_float(__builtin_amdgcn_ds_bpermute(src1, __float_as_int(t0)));
        float g5 = __int_as_float(__builtin_amdgcn_ds_bpermute(src1, __float_as_int(t1)));
        float g6 = __int_as_float(__builtin_amdgcn_ds_bpermute(src1, __float_as_int(t2)));
        float g7 = __int_as_float(__builtin_amdgcn_ds_bpermute(src1, __float_as_int(t3)));
        f16x8 b2f;
        b2f[0] = (_Float16)(live ? g0 : 0.f);
        b2f[1] = (_Float16)(live ? g1 : 0.f);
        b2f[2] = (_Float16)(live ? g2 : 0.f);
        b2f[3] = (_Float16)(live ? g3 : 0.f);
        b2f[4] = (_Float16)(live ? g4 : 0.f);
        b2f[5] = (_Float16)(live ? g5 : 0.f);
        b2f[6] = (_Float16)(live ? g6 : 0.f);
        b2f[7] = (_Float16)(live ? g7 : 0.f);

        f32x4 acc2 = {0.f, 0.f, 0.f, 0.f};
        acc2 = __builtin_amdgcn_mfma_f32_16x16x32_f16(a2f, b2f, acc2, 0, 0, 0);

        float u0 = fmaxf(acc2[0] + b2p.x, 0.f);
        float u1 = fmaxf(acc2[1] + b2p.y, 0.f);
        float u2 = fmaxf(acc2[2] + b2p.z, 0.f);
        float u3 = fmaxf(acc2[3] + b2p.w, 0.f);
        float s = u0 * wfp.x + u1 * wfp.y + u2 * wfp.z + u3 * wfp.w;
        s += __shfl_xor(s, 16, 64);
        s += __shfl_xor(s, 32, 64);
        if (hi == 0) out[t * 16 + n] = s + bf;
    }
}

extern "C" void kernel_launch(void* const* d_in, const int* in_sizes, int n_in,
                              void* d_out, int out_size, void* d_ws, size_t ws_size,
                              hipStream_t stream) {
    const float* x   = (const float*)d_in[0];
    // d_in[1] = edge_index — unused: row==col makes the conv identity+bias.
    const float* W1  = (const float*)d_in[2];
    const float* b1  = (const float*)d_in[3];
    const float* W2  = (const float*)d_in[4];
    const float* b2  = (const float*)d_in[5];
    const float* Wfc = (const float*)d_in[6];
    const float* bfc = (const float*)d_in[7];
    float* out = (float*)d_out;

    k_mlp_mfma<<<NBLK, 256, 0, stream>>>(x, W1, b1, W2, b2, Wfc, bfc, out);
}

// Round 10
// 22.301 us; speedup vs baseline: 1.1208x; 1.1208x over previous
//
#include <hip/hip_runtime.h>

#define TOT   400000            // B*N total nodes
#define FI    64                // in features
#define HD    16                // hidden dim
#define TILES (TOT / 16)        // 25000 16-node tiles
#define NBLK  2048
#define NWAVE (NBLK * 4)        // 256 threads = 4 waves per block

typedef _Float16 f16x8 __attribute__((ext_vector_type(8)));
typedef float    f32x4 __attribute__((ext_vector_type(4)));

// edge_index.expand(B,2,E).reshape(2,-1) makes row==col elementwise
// (flat idx = b*2E + r*E + e; +8E only shifts b by 4) -> every edge is a
// self-edge -> GCNConv == identity + bias. Network = per-node MLP:
//   out = relu(relu(x@W1+b1)@W2+b2)@Wfc + bfc
//
// Matrix pipe via SWAPPED operands (D = W^T . X^T), m89-verified layouts.
// Round 10: r4 structure (best, 22.2 us) with __launch_bounds__(256,5)
// (VGPR cap 102 -> 20 waves/CU, was 16). Occupancy probe: if flat, the
// ~4.7 TB/s read stream is this shape's ceiling (it already exceeds the
// read-side of the 6.29 TB/s bidirectional copy ubench) -> roofline.
__global__ __launch_bounds__(256, 5) void k_mlp_mfma(
        const float* __restrict__ x,
        const float* __restrict__ W1, const float* __restrict__ b1,
        const float* __restrict__ W2, const float* __restrict__ b2,
        const float* __restrict__ Wfc, const float* __restrict__ bfc,
        float* __restrict__ out) {
    const int lane = threadIdx.x & 63;
    const int n    = lane & 15;      // node-in-tile / D col
    const int hi   = lane >> 4;      // 0..3
    const int wid  = blockIdx.x * 4 + (threadIdx.x >> 6);

    // ---- weight fragments (VGPR-resident, wave-uniform source) ----
    f16x8 a1f[2];
#pragma unroll
    for (int ks = 0; ks < 2; ++ks)
#pragma unroll
        for (int i = 0; i < 8; ++i)
            a1f[ks][i] = (_Float16)W1[(ks * 32 + hi * 8 + i) * HD + n];

    f16x8 a2f;
    if (hi < 2) {
#pragma unroll
        for (int i = 0; i < 8; ++i)
            a2f[i] = (_Float16)W2[(hi * 8 + i) * HD + n];
    } else {
#pragma unroll
        for (int i = 0; i < 8; ++i)
            a2f[i] = (_Float16)0.0f;
    }

    const float4 b1p = *reinterpret_cast<const float4*>(b1 + hi * 4);
    const float4 b2p = *reinterpret_cast<const float4*>(b2 + hi * 4);
    const float4 wfp = *reinterpret_cast<const float4*>(Wfc + hi * 4);
    const float  bf  = bfc[0];

    // bpermute source lanes for layer-2 B-fragment assembly
    const int src0 = (((hi * 2)     & 3) * 16 + n) * 4;   // i = 0..3
    const int src1 = (((hi * 2 + 1) & 3) * 16 + n) * 4;   // i = 4..7
    const bool live = (hi < 2);                           // k<16 rows only

    for (int t = wid; t < TILES; t += NWAVE) {
        const float* xrow = x + ((size_t)t * 16 + n) * FI;

        float4 xa = *reinterpret_cast<const float4*>(xrow + hi * 8);
        float4 xb = *reinterpret_cast<const float4*>(xrow + hi * 8 + 4);
        float4 xc = *reinterpret_cast<const float4*>(xrow + 32 + hi * 8);
        float4 xd = *reinterpret_cast<const float4*>(xrow + 32 + hi * 8 + 4);

        f16x8 bA, bB;
        bA[0] = (_Float16)xa.x; bA[1] = (_Float16)xa.y;
        bA[2] = (_Float16)xa.z; bA[3] = (_Float16)xa.w;
        bA[4] = (_Float16)xb.x; bA[5] = (_Float16)xb.y;
        bA[6] = (_Float16)xb.z; bA[7] = (_Float16)xb.w;
        bB[0] = (_Float16)xc.x; bB[1] = (_Float16)xc.y;
        bB[2] = (_Float16)xc.z; bB[3] = (_Float16)xc.w;
        bB[4] = (_Float16)xd.x; bB[5] = (_Float16)xd.y;
        bB[6] = (_Float16)xd.z; bB[7] = (_Float16)xd.w;

        f32x4 acc = {0.f, 0.f, 0.f, 0.f};
        acc = __builtin_amdgcn_mfma_f32_16x16x32_f16(a1f[0], bA, acc, 0, 0, 0);
        acc = __builtin_amdgcn_mfma_f32_16x16x32_f16(a1f[1], bB, acc, 0, 0, 0);

        float t0 = fmaxf(acc[0] + b1p.x, 0.f);
        float t1 = fmaxf(acc[1] + b1p.y, 0.f);
        float t2 = fmaxf(acc[2] + b1p.z, 0.f);
        float t3 = fmaxf(acc[3] + b1p.w, 0.f);

        float g0 = __int_as_float(__builtin_amdgcn_ds_bpermute(src0, __float_as_int(t0)));
        float g1 = __int_as_float(__builtin_amdgcn_ds_bpermute(src0, __float_as_int(t1)));
        float g2 = __int_as_float(__builtin_amdgcn_ds_bpermute(src0, __float_as_int(t2)));
        float g3 = __int_as_float(__builtin_amdgcn_ds_bpermute(src0, __float_as_int(t3)));
        float g4 = __int_as_float(__builtin_amdgcn_ds_bpermute(src1, __float_as_int(t0)));
        float g5 = __int_as_float(__builtin_amdgcn_ds_bpermute(src1, __float_as_int(t1)));
        float g6 = __int_as_float(__builtin_amdgcn_ds_bpermute(src1, __float_as_int(t2)));
        float g7 = __int_as_float(__builtin_amdgcn_ds_bpermute(src1, __float_as_int(t3)));
        f16x8 b2f;
        b2f[0] = (_Float16)(live ? g0 : 0.f);
        b2f[1] = (_Float16)(live ? g1 : 0.f);
        b2f[2] = (_Float16)(live ? g2 : 0.f);
        b2f[3] = (_Float16)(live ? g3 : 0.f);
        b2f[4] = (_Float16)(live ? g4 : 0.f);
        b2f[5] = (_Float16)(live ? g5 : 0.f);
        b2f[6] = (_Float16)(live ? g6 : 0.f);
        b2f[7] = (_Float16)(live ? g7 : 0.f);

        f32x4 acc2 = {0.f, 0.f, 0.f, 0.f};
        acc2 = __builtin_amdgcn_mfma_f32_16x16x32_f16(a2f, b2f, acc2, 0, 0, 0);

        float u0 = fmaxf(acc2[0] + b2p.x, 0.f);
        float u1 = fmaxf(acc2[1] + b2p.y, 0.f);
        float u2 = fmaxf(acc2[2] + b2p.z, 0.f);
        float u3 = fmaxf(acc2[3] + b2p.w, 0.f);
        float s = u0 * wfp.x + u1 * wfp.y + u2 * wfp.z + u3 * wfp.w;
        s += __shfl_xor(s, 16, 64);
        s += __shfl_xor(s, 32, 64);
        if (hi == 0) out[t * 16 + n] = s + bf;
    }
}

extern "C" void kernel_launch(void* const* d_in, const int* in_sizes, int n_in,
                              void* d_out, int out_size, void* d_ws, size_t ws_size,
                              hipStream_t stream) {
    const float* x   = (const float*)d_in[0];
    // d_in[1] = edge_index — unused: row==col makes the conv identity+bias.
    const float* W1  = (const float*)d_in[2];
    const float* b1  = (const float*)d_in[3];
    const float* W2  = (const float*)d_in[4];
    const float* b2  = (const float*)d_in[5];
    const float* Wfc = (const float*)d_in[6];
    const float* bfc = (const float*)d_in[7];
    float* out = (float*)d_out;

    k_mlp_mfma<<<NBLK, 256, 0, stream>>>(x, W1, b1, W2, b2, Wfc, bfc, out);
}